// Round 1
// baseline (170.756 us; speedup 1.0000x reference)
//
#include <hip/hip_runtime.h>
#include <hip/hip_fp16.h>

#define BATCH 4096
#define HH 32
#define WW 32
#define KPROP 20
#define NACT 4
#define DIN 3072   // H*W*3
#define DPHI 2048  // 2*H*W
#define HWC 1024   // H*W
#define KC 1024    // compacted K (walls only)
#define TILE32 (32 * KC)   // one 32-row fragment-packed tile: [k/8][32][8]

typedef _Float16 h8_t __attribute__((ext_vector_type(8)));
typedef _Float16 h4_t __attribute__((ext_vector_type(4)));
typedef float f32x4 __attribute__((ext_vector_type(4)));
typedef float f32x16 __attribute__((ext_vector_type(16)));

__device__ inline float sigmoidf(float x) { return 1.0f / (1.0f + __expf(-x)); }

// DPP lane-shift helpers: 16-lane DPP rows; bound_ctrl=1 -> 0 at row edges.
__device__ inline float dpp_shr1(float x) {  // lane i <- lane i-1 (0 at i%16==0)
    return __int_as_float(__builtin_amdgcn_update_dpp(
        0, __float_as_int(x), 0x111, 0xF, 0xF, true));
}
__device__ inline float dpp_shl1(float x) {  // lane i <- lane i+1 (0 at i%16==15)
    return __int_as_float(__builtin_amdgcn_update_dpp(
        0, __float_as_int(x), 0x101, 0xF, 0xF, true));
}

// 32-row fragment-packed layout for mfma_32x32x16: P[t][ko][lm][j] with
// t=row/32, ko=k/8, lm=row%32, j=k%8. A wave's 32x16 fragment (lane l holds
// row=l&31, k=8*(l>>5)+j) is *contiguous*: elem offset = t*32768 + s*512 + 8*l
// for k-step s (since 256*(l>>5) + 8*(l&31) == 8*l).
__device__ inline size_t pack_off32(int row, int k) {
    return (size_t)(row >> 5) * TILE32 + (k >> 3) * 256 + (row & 31) * 8 + (k & 7);
}

// ------- P: fused prep. blocks [0,1024): pack walls (4 samples/block) + agent/goal idx.
//          blocks [1024,3072): Phi_w -> B_pack (32-row packed f16 walls) + Pag. -------
__global__ __launch_bounds__(256) void prep_fused_kernel(
    const float* __restrict__ obs,    // (4096, 3072)
    const float* __restrict__ Phi_w,  // (3072, 2048)
    _Float16* __restrict__ A_pack,    // (4096/32, 128, 32, 8)
    _Float16* __restrict__ B_pack,    // (2048/32, 128, 32, 8): element (n,c) = Phi_w[3c][n]
    _Float16* __restrict__ Pag,       // (2, 1024, 2048)
    int* __restrict__ aidx, int* __restrict__ gidx)
{
    if (blockIdx.x < BATCH / 4) {
        // 4 samples per block: the 4 waves complete each 64B A_pack sector
        // ((row&31) slots 4-consecutive) inside one block -> full-sector writes.
        const int b  = blockIdx.x * 4 + (threadIdx.x >> 6);
        const int c0 = (threadIdx.x & 63) * 16;           // 16 cells/thread
        const float4* src = (const float4*)(obs + (size_t)b * DIN + 3 * c0);
        float4 f[12];
        #pragma unroll
        for (int i = 0; i < 12; i++) f[i] = src[i];       // 192B/thread, 12-deep MLP
        _Float16 wv[16];
        #pragma unroll
        for (int g = 0; g < 4; g++) {
            const float4 fa = f[3*g], fb = f[3*g+1], fc = f[3*g+2];
            wv[4*g+0] = (_Float16)fa.x; wv[4*g+1] = (_Float16)fa.w;
            wv[4*g+2] = (_Float16)fb.z; wv[4*g+3] = (_Float16)fc.y;
            const int cc = c0 + 4 * g;
            if (fa.y > 0.5f) aidx[b] = cc;
            if (fb.x > 0.5f) aidx[b] = cc + 1;
            if (fb.w > 0.5f) aidx[b] = cc + 2;
            if (fc.z > 0.5f) aidx[b] = cc + 3;
            if (fa.z > 0.5f) gidx[b] = cc;
            if (fb.y > 0.5f) gidx[b] = cc + 1;
            if (fc.x > 0.5f) gidx[b] = cc + 2;
            if (fc.w > 0.5f) gidx[b] = cc + 3;
        }
        *(h8_t*)(A_pack + pack_off32(b, c0))     = *(h8_t*)&wv[0];
        *(h8_t*)(A_pack + pack_off32(b, c0 + 8)) = *(h8_t*)&wv[8];
    } else {
        const int bid = blockIdx.x - BATCH / 4; // 0..2047
        const int ni = bid & 63;                // n tile (32 wide)
        const int ci = bid >> 6;                // c tile (32 wide)
        const int tx = threadIdx.x & 31;
        const int ty = threadIdx.x >> 5;        // 0..7
        const int n  = ni * 32 + tx;
        const int c0 = ci * 32 + ty * 4;        // 4 consecutive c per thread -> h4 write
        h4_t wq;
        #pragma unroll
        for (int i = 0; i < 4; i++) {
            const int c = c0 + i;
            wq[i] = (_Float16)Phi_w[(size_t)(3 * c) * DPHI + n];
            Pag[(size_t)c * DPHI + n]         = (_Float16)Phi_w[(size_t)(3 * c + 1) * DPHI + n];
            Pag[(size_t)(HWC + c) * DPHI + n] = (_Float16)Phi_w[(size_t)(3 * c + 2) * DPHI + n];
        }
        *(h4_t*)(B_pack + pack_off32(n, c0)) = wq;  // transpose via packed 8B scatter
    }
}

// ---------------- GEMM: pre = walls @ wallsW^T + bias, f16 out ----------------
// LDS-free, barrier-free, 32x32x16 MFMA (half the MFMA instructions of 16x16x32
// at the higher 32x32 rate; identical operand bytes). Operands 32-row
// fragment-packed -> each wave fragment load is 1 KB contiguous
// (elem offset = tile*32768 + s*512 + 8*lane). Even/odd register buffers
// (no copies) keep one buffer's 8 loads in flight while MFMA runs on the
// other (partial-vmcnt pipeline). 64x64/wave (2x2 of 32x32), 4 waves/block.
__global__ __launch_bounds__(256) void gemm_pre_kernel(
    const _Float16* __restrict__ A_pack,  // (128, 32768)
    const _Float16* __restrict__ B_pack,  // (64, 32768)
    const float* __restrict__ bias,       // (2048,)
    _Float16* __restrict__ pre)           // (4096, 2048)
{
    const int tid  = threadIdx.x;
    const int lane = tid & 63;
    const int wid  = tid >> 6;
    const int m0 = blockIdx.y * 64;                 // 64 rows/block
    const int n0 = blockIdx.x * 256 + wid * 64;     // 64 cols/wave

    const _Float16* Abase = A_pack + (size_t)(blockIdx.y * 2) * TILE32 + 8 * lane;
    const _Float16* Bbase = B_pack + (size_t)(blockIdx.x * 8 + wid * 2) * TILE32 + 8 * lane;

    f32x16 acc[2][2] = {};
    h8_t a0[2][2], b0[2][2], a1[2][2], b1[2][2];    // [m/n tile][k-step within buffer]

    #pragma unroll
    for (int t = 0; t < 2; t++)
        #pragma unroll
        for (int q = 0; q < 2; q++) {
            a0[t][q] = *(const h8_t*)(Abase + t * TILE32 + q * 512);
            b0[t][q] = *(const h8_t*)(Bbase + t * TILE32 + q * 512);
            a1[t][q] = *(const h8_t*)(Abase + t * TILE32 + (2 + q) * 512);
            b1[t][q] = *(const h8_t*)(Bbase + t * TILE32 + (2 + q) * 512);
        }

    for (int s0 = 0; s0 < 64; s0 += 4) {            // k-step = 16; 4 steps/iter
        #pragma unroll
        for (int q = 0; q < 2; q++)
            #pragma unroll
            for (int mt = 0; mt < 2; mt++)
                #pragma unroll
                for (int nt = 0; nt < 2; nt++)
                    acc[mt][nt] = __builtin_amdgcn_mfma_f32_32x32x16_f16(
                        a0[mt][q], b0[nt][q], acc[mt][nt], 0, 0, 0);
        if (s0 + 4 < 64) {
            #pragma unroll
            for (int t = 0; t < 2; t++)
                #pragma unroll
                for (int q = 0; q < 2; q++) {
                    a0[t][q] = *(const h8_t*)(Abase + t * TILE32 + (s0 + 4 + q) * 512);
                    b0[t][q] = *(const h8_t*)(Bbase + t * TILE32 + (s0 + 4 + q) * 512);
                }
        }
        #pragma unroll
        for (int q = 0; q < 2; q++)
            #pragma unroll
            for (int mt = 0; mt < 2; mt++)
                #pragma unroll
                for (int nt = 0; nt < 2; nt++)
                    acc[mt][nt] = __builtin_amdgcn_mfma_f32_32x32x16_f16(
                        a1[mt][q], b1[nt][q], acc[mt][nt], 0, 0, 0);
        if (s0 + 6 < 64) {
            #pragma unroll
            for (int t = 0; t < 2; t++)
                #pragma unroll
                for (int q = 0; q < 2; q++) {
                    a1[t][q] = *(const h8_t*)(Abase + t * TILE32 + (s0 + 6 + q) * 512);
                    b1[t][q] = *(const h8_t*)(Bbase + t * TILE32 + (s0 + 6 + q) * 512);
                }
        }
    }

    // C/D layout (HW-verified): col = lane&31, row = (reg&3) + 8*(reg>>2) + 4*(lane>>5).
    // Adjacent lanes are adjacent cols -> stores coalesce as 64B runs.
    const int cl  = lane & 31;
    const int rhi = (lane >> 5) * 4;
    #pragma unroll
    for (int nt = 0; nt < 2; nt++) {
        const int col = n0 + nt * 32 + cl;
        const float bcol = bias[col];
        #pragma unroll
        for (int mt = 0; mt < 2; mt++) {
            #pragma unroll
            for (int r = 0; r < 16; r++) {
                const int row = m0 + mt * 32 + rhi + (r & 3) + 8 * (r >> 2);
                pre[(size_t)row * DPHI + col] = (_Float16)(acc[mt][nt][r] + bcol);
            }
        }
    }
}

// ---------------- B: sigmoid + 20-step vprop in registers + head MLP ----------------
__global__ __launch_bounds__(256, 4) void vprop_head_kernel(
    const _Float16* __restrict__ pre,  // (4096, 2048)
    const _Float16* __restrict__ Pag,  // (2, 1024, 2048)
    const float* __restrict__ obs,     // (4096, 3072)
    const int* __restrict__ aidx,
    const int* __restrict__ gidx,
    const float* __restrict__ L1w,     // (36,16)
    const float* __restrict__ L1b,
    const float* __restrict__ L2w,     // (16,4)
    const float* __restrict__ L2b,
    float* __restrict__ out)           // (4096, 4)
{
    __shared__ __align__(16) float Vg[4][HWC];
    __shared__ float sel[4][36], hbuf[4][16];

    const int tid  = threadIdx.x;
    const int w    = tid >> 6;
    const int lane = tid & 63;
    const int b    = blockIdx.x * 4 + w;
    const int bi   = lane & 15;
    const int bj   = lane >> 4;
    const int ai = aidx[b];
    const int gi = gidx[b];

    const _Float16* pb = pre + (size_t)b * DPHI;
    const _Float16* ra = Pag + (size_t)ai * DPHI;
    const _Float16* rg = Pag + (size_t)(HWC + gi) * DPHI;

    float v[2][8], p[2][8], a[2][8];
    #pragma unroll
    for (int r = 0; r < 2; r++) {
        const int off = 64 * (2 * bi + r) + 16 * bj;
        const h8_t ph0 = *(const h8_t*)(pb + off), ph1 = *(const h8_t*)(pb + off + 8);
        const h8_t pa0 = *(const h8_t*)(ra + off), pa1 = *(const h8_t*)(ra + off + 8);
        const h8_t pg0 = *(const h8_t*)(rg + off), pg1 = *(const h8_t*)(rg + off + 8);
        #pragma unroll
        for (int c = 0; c < 4; c++) {
            const float rv = sigmoidf((float)ph0[2*c]   + (float)pa0[2*c]   + (float)pg0[2*c]);
            const float pv = sigmoidf((float)ph0[2*c+1] + (float)pa0[2*c+1] + (float)pg0[2*c+1]);
            v[r][c] = rv; p[r][c] = pv; a[r][c] = rv * (1.0f - pv);
            const float rv2 = sigmoidf((float)ph1[2*c]   + (float)pa1[2*c]   + (float)pg1[2*c]);
            const float pv2 = sigmoidf((float)ph1[2*c+1] + (float)pa1[2*c+1] + (float)pg1[2*c+1]);
            v[r][c+4] = rv2; p[r][c+4] = pv2; a[r][c+4] = rv2 * (1.0f - pv2);
        }
    }

    for (int it = 0; it < KPROP; it++) {
        float uh[8], dh[8], lh[2], rh[2];
        #pragma unroll
        for (int c = 0; c < 8; c++) {
            uh[c] = dpp_shr1(v[1][c]);
            dh[c] = dpp_shl1(v[0][c]);
        }
        #pragma unroll
        for (int r = 0; r < 2; r++) {
            lh[r] = __shfl(v[r][7], lane - 16);
            rh[r] = __shfl(v[r][0], lane + 16);
            if (bj == 0) lh[r] = 0.0f;
            if (bj == 3) rh[r] = 0.0f;
        }
        float nb[2][8];
        #pragma unroll
        for (int c = 0; c < 8; c++) {
            const float lf0 = (c == 0) ? lh[0] : v[0][c-1];
            const float rt0 = (c == 7) ? rh[0] : v[0][c+1];
            const float lf1 = (c == 0) ? lh[1] : v[1][c-1];
            const float rt1 = (c == 7) ? rh[1] : v[1][c+1];
            nb[0][c] = fmaxf(fmaxf(uh[c], v[1][c]), fmaxf(lf0, rt0));
            nb[1][c] = fmaxf(fmaxf(v[0][c], dh[c]), fmaxf(lf1, rt1));
        }
        #pragma unroll
        for (int r = 0; r < 2; r++)
            #pragma unroll
            for (int c = 0; c < 8; c++)
                v[r][c] = fmaxf(v[r][c], fmaf(p[r][c], nb[r][c], a[r][c]));
    }

    #pragma unroll
    for (int r = 0; r < 2; r++) {
        float4 lo, hi;
        lo.x = v[r][0]; lo.y = v[r][1]; lo.z = v[r][2]; lo.w = v[r][3];
        hi.x = v[r][4]; hi.y = v[r][5]; hi.z = v[r][6]; hi.w = v[r][7];
        const int base = (2 * bi + r) * 32 + 8 * bj;
        *(float4*)&Vg[w][base]     = lo;
        *(float4*)&Vg[w][base + 4] = hi;
    }
    __syncthreads();

    const int pi = ai >> 5, pj = ai & 31;
    if (lane < 36) {
        const int cell = lane >> 2;
        const int ch = lane & 3;
        const int di = pi + cell / 3 - 1;
        const int dj = pj + cell % 3 - 1;
        float vv = 0.0f;
        if (di >= 0 && di < HH && dj >= 0 && dj < WW) {
            const int c = di * WW + dj;
            vv = (ch < 3) ? obs[(size_t)b * DIN + 3 * c + ch] : Vg[w][c];
        }
        sel[w][lane] = vv;
    }
    __syncthreads();

    if (lane < 16) {
        float h = L1b[lane];
        #pragma unroll
        for (int k = 0; k < 36; k++) h += sel[w][k] * L1w[k * 16 + lane];
        hbuf[w][lane] = fmaxf(h, 0.0f);
    }
    __syncthreads();

    if (lane < 4) {
        float o = L2b[lane];
        #pragma unroll
        for (int t = 0; t < 16; t++) o += hbuf[w][t] * L2w[t * 4 + lane];
        out[(size_t)b * NACT + lane] = o;
    }
}

extern "C" void kernel_launch(void* const* d_in, const int* in_sizes, int n_in,
                              void* d_out, int out_size, void* d_ws, size_t ws_size,
                              hipStream_t stream) {
    const float* obs   = (const float*)d_in[0];
    const float* Phi_w = (const float*)d_in[1];
    const float* Phi_b = (const float*)d_in[2];
    const float* L1w   = (const float*)d_in[3];
    const float* L1b   = (const float*)d_in[4];
    const float* L2w   = (const float*)d_in[5];
    const float* L2b   = (const float*)d_in[6];
    float* out = (float*)d_out;

    char* ws = (char*)d_ws;
    _Float16* pre    = (_Float16*)ws;                  // 16,777,216 B
    _Float16* A_pack = (_Float16*)(ws + 16777216);     //  8,388,608 B
    _Float16* B_pack = (_Float16*)(ws + 25165824);     //  4,194,304 B
    _Float16* Pag    = (_Float16*)(ws + 29360128);     //  8,388,608 B
    int* aidx = (int*)(ws + 37748736);                 //     16,384 B
    int* gidx = aidx + BATCH;                          //     16,384 B

    prep_fused_kernel<<<BATCH / 4 + 2048, 256, 0, stream>>>(obs, Phi_w, A_pack, B_pack, Pag, aidx, gidx);
    gemm_pre_kernel<<<dim3(DPHI / 256, BATCH / 64), 256, 0, stream>>>(A_pack, B_pack, Phi_b, pre);
    vprop_head_kernel<<<BATCH / 4, 256, 0, stream>>>(pre, Pag, obs, aidx, gidx,
                                                     L1w, L1b, L2w, L2b, out);
}